// Round 13
// baseline (584.164 us; speedup 1.0000x reference)
//
#include <hip/hip_runtime.h>
#include <hip/hip_bf16.h>

#define NPIX   65536
#define TT     5
#define CC     10
#define HH     32
#define WIDTH  64
#define KW     32
#define OUTC   10

// ---- workspace layout (float offsets) ----
#define OFF_L0I    0        // 1280  [c][j][g]
#define OFF_L0H    1280     // 4096  [k][j][g]
#define OFF_L1I    5376     // 4096
#define OFF_L1H    9472     // 4096
#define OFF_B0     13568    // 128   [j][g]
#define OFF_B1     13696    // 128
#define OFF_FC1W   13824    // 2048  [k][ch]
#define OFF_FC1B   15872    // 64
#define OFF_CWT2   16384    // 16384 [k][ci][co]  (straight copy of conv_w)
#define OFF_CB     32768    // 256
#define OFF_FC2W2  33024    // 2048  [m2][ch] float2
#define OFF_FC2B   35072    // 32
#define OFF_FC3W4  35104    // 320   [oc2][m2] float4
#define OFF_FC3B   35424    // 16
#define OFF_GW     35440    // 8
#define OFF_FEATS_A 36864
#define OFF_FEATS_B (36864 + 8388608)

#define STRAIGHT_ATTR_IDX (65025 * 3)

__device__ __forceinline__ float sigf(float x)  { return 1.0f / (1.0f + __expf(-x)); }
__device__ __forceinline__ float tanhf_(float x){ return 1.0f - 2.0f / (__expf(2.0f * x) + 1.0f); }

// ---------------- prep: pack params ----------------
__global__ __launch_bounds__(256, 1)
void prep_kernel(const float* Wih0, const float* Whh0,
                 const float* bih0, const float* bhh0,
                 const float* Wih1, const float* Whh1,
                 const float* bih1, const float* bhh1,
                 const float* fc1w, const float* fc1b,
                 const float* convw, const float* convb,
                 const float* fc2w, const float* fc2b,
                 const float* fc3w, const float* fc3b,
                 const float* gparam, const float* eattr,
                 float* P) {
    int tid = blockIdx.x * blockDim.x + threadIdx.x;
    int stride = gridDim.x * blockDim.x;
    // LSTM k-major: [k][j][g] <- W[(g*32+j)*K + k]
    for (int idx = tid; idx < 1280; idx += stride) {
        int g = idx & 3, j = (idx >> 2) & 31, c = idx >> 7;
        P[OFF_L0I + idx] = Wih0[(g * 32 + j) * 10 + c];
    }
    for (int idx = tid; idx < 4096; idx += stride) {
        int g = idx & 3, j = (idx >> 2) & 31, k = idx >> 7;
        P[OFF_L0H + idx] = Whh0[(g * 32 + j) * 32 + k];
        P[OFF_L1I + idx] = Wih1[(g * 32 + j) * 32 + k];
        P[OFF_L1H + idx] = Whh1[(g * 32 + j) * 32 + k];
    }
    for (int idx = tid; idx < 128; idx += stride) {
        int g = idx & 3, j = idx >> 2;
        P[OFF_B0 + idx] = bih0[g * 32 + j] + bhh0[g * 32 + j];
        P[OFF_B1 + idx] = bih1[g * 32 + j] + bhh1[g * 32 + j];
    }
    // fc1 k-major [k][ch]
    for (int idx = tid; idx < 2048; idx += stride) {
        int ch = idx & 63, k = idx >> 6;
        P[OFF_FC1W + idx] = fc1w[ch * 32 + k];
    }
    for (int i = tid; i < 64; i += stride) P[OFF_FC1B + i] = fc1b[i];
    // conv: straight copy, [k][ci][co] (convw native layout)
    for (int idx = tid; idx < 16384; idx += stride)
        P[OFF_CWT2 + idx] = convw[idx];
    for (int i = tid; i < 256; i += stride) P[OFF_CB + i] = convb[i];
    for (int idx = tid; idx < 2048; idx += stride) {
        int e = idx >> 1, h = idx & 1, m2 = e >> 6, ch = e & 63;
        P[OFF_FC2W2 + idx] = fc2w[(2 * m2 + h) * 64 + ch];
    }
    for (int i = tid; i < 32;  i += stride) P[OFF_FC2B + i] = fc2b[i];
    for (int idx = tid; idx < 320; idx += stride) {
        int q = idx & 3, e = idx >> 2, oc2 = e >> 4, m2 = e & 15;
        int oc = 2 * oc2 + (q & 1), m = 2 * m2 + (q >> 1);
        P[OFF_FC3W4 + idx] = fc3w[oc * 32 + m];
    }
    for (int i = tid; i < 10; i += stride) P[OFF_FC3B + i] = fc3b[i];
    for (int idx = tid; idx < 8; idx += stride) {
        int k = idx >> 1;
        float g = gparam[k];
        float denom = g * g + 1e-8f;
        float a = (idx & 1) ? eattr[0] : eattr[STRAIGHT_ATTR_IDX];
        P[OFF_GW + idx] = __expf(-(a * a) / denom);
    }
}

// ---------------- LSTM: 4-way wave j-split, 2 pixels per lane ----------------
// DISCRIMINATING EXPERIMENT (R0-R12 invariant: ~4 issue-cyc per FMA).
// Theory (a) codegen: each SGPR weight is v_mov'd to VGPR then used once ->
//   2 px/lane amortizes the mov over 2 FMAs -> ~3 cyc/FMA -> lstm ~250us.
// Theory (b) HW: v_fma with SGPR operand is half-rate -> unchanged ~330us.
// 256 thr = 4 waves over 128 px; wave w owns units [8w,8w+8); lane owns px
// pair (even-aligned -> float2 x/H/feats accesses). Register peak ~128;
// spill tripwire = FETCH >> 14MB. launch_bounds arg2 stays 1 (R1/R2/R8).
#define ROW_ACC2(WBASE, SA, SB) do {                                \
    const float* wr_ = (WBASE); float sa_ = (SA), sb_ = (SB);       \
    _Pragma("unroll")                                               \
    for (int q_ = 0; q_ < 32; q_++) {                               \
        float wv_ = wr_[q_];                                        \
        za[q_] = __builtin_fmaf(wv_, sa_, za[q_]);                  \
        zb[q_] = __builtin_fmaf(wv_, sb_, zb[q_]);                  \
    } } while (0)

__global__ __launch_bounds__(256, 1)
void lstm_fc1_kernel(const float* __restrict__ x,
                     const float* __restrict__ P,
                     float* __restrict__ feats) {
    __shared__ float H0[HH * 128];   // 16384 B  [j][pxl]
    __shared__ float H1[HH * 128];   // 16384 B

    int tid  = threadIdx.x;
    int w    = __builtin_amdgcn_readfirstlane(tid >> 6);  // wave id 0..3
    int lane = tid & 63;
    int jw   = w << 3;               // first owned unit
    int w32  = w << 5;               // float offset into 128-wide gate rows
    int pxl  = lane << 1;            // local pixel pair base (even)

    int n = blockIdx.x * 128 + pxl;  // 65536 % 128 == 0 -> pair never crosses b
    int b = n >> 16;
    int pix = n & (NPIX - 1);
    const float* xb = x + (size_t)b * TT * CC * NPIX + pix;

    float c0a[8], c0b[8], c1a[8], c1b[8];
#pragma unroll
    for (int j = 0; j < 8; j++) {
        c0a[j] = 0.f; c0b[j] = 0.f; c1a[j] = 0.f; c1b[j] = 0.f;
        *(float2*)&H0[(jw + j) * 128 + pxl] = make_float2(0.f, 0.f);
        *(float2*)&H1[(jw + j) * 128 + pxl] = make_float2(0.f, 0.f);
    }
    __syncthreads();

#pragma unroll 1
    for (int t = 0; t < TT; t++) {
        float2 xcur[CC];
#pragma unroll
        for (int c = 0; c < CC; c++)
            xcur[c] = *(const float2*)(xb + (size_t)(t * CC + c) * NPIX);

        // ---- layer 0 ----
        {
            float za[32], zb[32];
            const float* bbp = P + OFF_B0 + w32;
#pragma unroll
            for (int q = 0; q < 32; q++) { float bv = bbp[q]; za[q] = bv; zb[q] = bv; }
#pragma unroll 1
            for (int c = 0; c < CC; c++)
                ROW_ACC2(P + OFF_L0I + c * 128 + w32, xcur[c].x, xcur[c].y);
#pragma unroll 1
            for (int k = 0; k < HH; k++) {
                float2 hv = *(const float2*)&H0[k * 128 + pxl];   // h0(t-1)
                ROW_ACC2(P + OFF_L0H + k * 128 + w32, hv.x, hv.y);
            }
            __syncthreads();                      // all waves done reading old H0
#pragma unroll
            for (int j = 0; j < 8; j++) {
                float cna = sigf(za[4 * j + 1]) * c0a[j]
                          + sigf(za[4 * j + 0]) * tanhf_(za[4 * j + 2]);
                float cnb = sigf(zb[4 * j + 1]) * c0b[j]
                          + sigf(zb[4 * j + 0]) * tanhf_(zb[4 * j + 2]);
                c0a[j] = cna; c0b[j] = cnb;
                *(float2*)&H0[(jw + j) * 128 + pxl] =
                    make_float2(sigf(za[4 * j + 3]) * tanhf_(cna),
                                sigf(zb[4 * j + 3]) * tanhf_(cnb));
            }
            __syncthreads();                      // new H0 visible
        }

        // ---- layer 1 ----
        {
            float za[32], zb[32];
            const float* bbp = P + OFF_B1 + w32;
#pragma unroll
            for (int q = 0; q < 32; q++) { float bv = bbp[q]; za[q] = bv; zb[q] = bv; }
#pragma unroll 1
            for (int k = 0; k < HH; k++) {
                float2 hv = *(const float2*)&H0[k * 128 + pxl];   // h0(t)
                ROW_ACC2(P + OFF_L1I + k * 128 + w32, hv.x, hv.y);
            }
#pragma unroll 1
            for (int k = 0; k < HH; k++) {
                float2 hv = *(const float2*)&H1[k * 128 + pxl];   // h1(t-1)
                ROW_ACC2(P + OFF_L1H + k * 128 + w32, hv.x, hv.y);
            }
            __syncthreads();                      // all waves done reading old H1
#pragma unroll
            for (int j = 0; j < 8; j++) {
                float cna = sigf(za[4 * j + 1]) * c1a[j]
                          + sigf(za[4 * j + 0]) * tanhf_(za[4 * j + 2]);
                float cnb = sigf(zb[4 * j + 1]) * c1b[j]
                          + sigf(zb[4 * j + 0]) * tanhf_(zb[4 * j + 2]);
                c1a[j] = cna; c1b[j] = cnb;
                *(float2*)&H1[(jw + j) * 128 + pxl] =
                    make_float2(sigf(za[4 * j + 3]) * tanhf_(cna),
                                sigf(zb[4 * j + 3]) * tanhf_(cnb));
            }
            __syncthreads();                      // new H1 visible
        }
    }

    // ---- fc1 + relu: wave w computes ch in [16w, 16w+16) for both pixels ----
    float fa[16], fb[16];
    {
        const float* fb1 = P + OFF_FC1B + (w << 4);
#pragma unroll
        for (int m = 0; m < 16; m++) { float bv = fb1[m]; fa[m] = bv; fb[m] = bv; }
    }
#pragma unroll 1
    for (int k = 0; k < HH; k++) {
        float2 hv = *(const float2*)&H1[k * 128 + pxl];
        const float* wr = P + OFF_FC1W + k * 64 + (w << 4);
#pragma unroll
        for (int m = 0; m < 16; m++) {
            float wv = wr[m];
            fa[m] = __builtin_fmaf(wv, hv.x, fa[m]);
            fb[m] = __builtin_fmaf(wv, hv.y, fb[m]);
        }
    }
    float* fob = feats + (size_t)b * WIDTH * NPIX + (size_t)(w * 16) * NPIX + pix;
#pragma unroll
    for (int m = 0; m < 16; m++)
        *(float2*)(fob + (size_t)m * NPIX) =
            make_float2(fmaxf(fa[m], 0.f), fmaxf(fb[m], 0.f));
}

// ---------------- fused conv layer: U-in-LDS, 4 px x 16 outs per lane ----------------
// R12 structure (-25us over R8). This round: ci-loop unroll 2 to pipeline the
// U/W ds_reads (was unroll 1 -> serialized read->wait->FMA per ci).
__global__ __launch_bounds__(256, 1)
void conv_fused_kernel(const float* __restrict__ Fin, float* __restrict__ Fout,
                       const float* __restrict__ P, int k) {
    __shared__ float US[64 * 256];   // 65536 B  [ci][px]
    __shared__ float CW[64 * 64];    // 16384 B  [ci][co]

    int tid = threadIdx.x;
    {
        const float4* src = (const float4*)(P + OFF_CWT2 + k * 4096);
        float4* dst = (float4*)CW;
        for (int idx = tid; idx < 1024; idx += 256) dst[idx] = src[idx];
    }

    int n = blockIdx.x * 256 + tid;
    int b = n >> 16;
    int pix = n & (NPIX - 1);
    int i = pix >> 8, j = pix & 255;
    float wstr = P[OFF_GW + 2 * k], wdiag = P[OFF_GW + 2 * k + 1];
    float fu = (i > 0) ? wstr : 0.f, fd = (i < 255) ? wstr : 0.f;
    float fl = (j > 0) ? wstr : 0.f, fr = (j < 255) ? wstr : 0.f;
    float ful = (i > 0 && j > 0) ? wdiag : 0.f, fur = (i > 0 && j < 255) ? wdiag : 0.f;
    float fdl = (i < 255 && j > 0) ? wdiag : 0.f, fdr = (i < 255 && j < 255) ? wdiag : 0.f;

    const float* fb = Fin + (size_t)b * WIDTH * NPIX + pix;
#pragma unroll
    for (int ch = 0; ch < WIDTH; ch++) {
        const float* yc = fb + (size_t)ch * NPIX;
        float v = yc[0];
        v += fu * yc[-256] + fd * yc[256] + fl * yc[-1] + fr * yc[1];
        v += ful * yc[-257] + fur * yc[-255] + fdl * yc[255] + fdr * yc[257];
        US[ch * 256 + tid] = v;
    }
    __syncthreads();

    int l = tid & 63;
    int ob16 = (tid >> 6) << 4;          // wave's first output channel
    float4 acc[16];
#pragma unroll
    for (int o = 0; o < 16; o++) {
        float bv = P[OFF_CB + k * 64 + ob16 + o];
        acc[o] = make_float4(bv, bv, bv, bv);
    }
    const float4* US4 = (const float4*)US;
#pragma unroll 2
    for (int ci = 0; ci < 64; ci++) {
        float4 u4 = US4[ci * 64 + l];
        const float4* wr4 = (const float4*)(CW + ci * 64 + ob16);
#pragma unroll
        for (int q = 0; q < 4; q++) {
            float4 wq = wr4[q];
            acc[4 * q + 0].x = __builtin_fmaf(wq.x, u4.x, acc[4 * q + 0].x);
            acc[4 * q + 0].y = __builtin_fmaf(wq.x, u4.y, acc[4 * q + 0].y);
            acc[4 * q + 0].z = __builtin_fmaf(wq.x, u4.z, acc[4 * q + 0].z);
            acc[4 * q + 0].w = __builtin_fmaf(wq.x, u4.w, acc[4 * q + 0].w);
            acc[4 * q + 1].x = __builtin_fmaf(wq.y, u4.x, acc[4 * q + 1].x);
            acc[4 * q + 1].y = __builtin_fmaf(wq.y, u4.y, acc[4 * q + 1].y);
            acc[4 * q + 1].z = __builtin_fmaf(wq.y, u4.z, acc[4 * q + 1].z);
            acc[4 * q + 1].w = __builtin_fmaf(wq.y, u4.w, acc[4 * q + 1].w);
            acc[4 * q + 2].x = __builtin_fmaf(wq.z, u4.x, acc[4 * q + 2].x);
            acc[4 * q + 2].y = __builtin_fmaf(wq.z, u4.y, acc[4 * q + 2].y);
            acc[4 * q + 2].z = __builtin_fmaf(wq.z, u4.z, acc[4 * q + 2].z);
            acc[4 * q + 2].w = __builtin_fmaf(wq.z, u4.w, acc[4 * q + 2].w);
            acc[4 * q + 3].x = __builtin_fmaf(wq.w, u4.x, acc[4 * q + 3].x);
            acc[4 * q + 3].y = __builtin_fmaf(wq.w, u4.y, acc[4 * q + 3].y);
            acc[4 * q + 3].z = __builtin_fmaf(wq.w, u4.z, acc[4 * q + 3].z);
            acc[4 * q + 3].w = __builtin_fmaf(wq.w, u4.w, acc[4 * q + 3].w);
        }
    }

    int pn = blockIdx.x * 256 + 4 * l;   // first of this lane's 4 pixels
    int pb = pn >> 16;
    int ppix = pn & (NPIX - 1);
    float* ob = Fout + (size_t)pb * WIDTH * NPIX + ppix;
#pragma unroll
    for (int o = 0; o < 16; o++) {
        float4 r;
        r.x = fmaxf(acc[o].x, 0.f); r.y = fmaxf(acc[o].y, 0.f);
        r.z = fmaxf(acc[o].z, 0.f); r.w = fmaxf(acc[o].w, 0.f);
        *(float4*)(ob + (size_t)(ob16 + o) * NPIX) = r;
    }
}

// ---------------- last conv (no relu) + fc2/fc3 head (R12 exact) ----------------
__global__ __launch_bounds__(256, 1)
void conv_head_kernel(const float* __restrict__ Fin, const float* __restrict__ P,
                      float* __restrict__ out) {
    const int k = 3;
    __shared__ float4 CW3[1024];
    __shared__ float  CB3[64];
    __shared__ float4 F2W[512];
    __shared__ float  F2B[32];
    __shared__ float4 F3W[80];
    __shared__ float  F3B[12];
    {
        const float* wsrc = P + OFF_CWT2 + k * 4096;   // [ci][co]
        for (int idx = threadIdx.x; idx < 1024; idx += 256) {
            int co2 = idx >> 5, ci2 = idx & 31;
            CW3[idx] = make_float4(wsrc[(2 * ci2) * 64 + 2 * co2],
                                   wsrc[(2 * ci2) * 64 + 2 * co2 + 1],
                                   wsrc[(2 * ci2 + 1) * 64 + 2 * co2],
                                   wsrc[(2 * ci2 + 1) * 64 + 2 * co2 + 1]);
        }
        const float4* s2 = (const float4*)(P + OFF_FC2W2);
        for (int i = threadIdx.x; i < 512; i += 256) F2W[i] = s2[i];
        const float4* s3 = (const float4*)(P + OFF_FC3W4);
        if (threadIdx.x < 80) F3W[threadIdx.x] = s3[threadIdx.x];
        if (threadIdx.x < 64) CB3[threadIdx.x] = P[OFF_CB + k * 64 + threadIdx.x];
        if (threadIdx.x < 32) F2B[threadIdx.x] = P[OFF_FC2B + threadIdx.x];
        if (threadIdx.x < 10) F3B[threadIdx.x] = P[OFF_FC3B + threadIdx.x];
    }
    __syncthreads();

    int n = blockIdx.x * 256 + threadIdx.x;
    int b = n >> 16;
    int pix = n & (NPIX - 1);
    int i = pix >> 8, j = pix & 255;
    float wstr = P[OFF_GW + 2 * k], wdiag = P[OFF_GW + 2 * k + 1];
    float fu = (i > 0) ? wstr : 0.f, fd = (i < 255) ? wstr : 0.f;
    float fl = (j > 0) ? wstr : 0.f, fr = (j < 255) ? wstr : 0.f;
    float ful = (i > 0 && j > 0) ? wdiag : 0.f, fur = (i > 0 && j < 255) ? wdiag : 0.f;
    float fdl = (i < 255 && j > 0) ? wdiag : 0.f, fdr = (i < 255 && j < 255) ? wdiag : 0.f;

    const float* fb = Fin + (size_t)b * WIDTH * NPIX + pix;
    float u[WIDTH];
#pragma unroll
    for (int ch = 0; ch < WIDTH; ch++) {
        const float* yc = fb + (size_t)ch * NPIX;
        float v = yc[0];
        v += fu * yc[-256] + fd * yc[256] + fl * yc[-1] + fr * yc[1];
        v += ful * yc[-257] + fur * yc[-255] + fdl * yc[255] + fdr * yc[257];
        u[ch] = v;
    }

    float f[WIDTH];
#pragma unroll
    for (int co2 = 0; co2 < 32; co2++) {
        float ax = CB3[2 * co2], ay = CB3[2 * co2 + 1];
        const float4* wv = CW3 + co2 * 32;
#pragma unroll
        for (int ci2 = 0; ci2 < 32; ci2++) {
            float4 q = wv[ci2];
            float a0 = u[2 * ci2], a1 = u[2 * ci2 + 1];
            ax = __builtin_fmaf(q.x, a0, ax); ax = __builtin_fmaf(q.z, a1, ax);
            ay = __builtin_fmaf(q.y, a0, ay); ay = __builtin_fmaf(q.w, a1, ay);
        }
        f[2 * co2] = ax; f[2 * co2 + 1] = ay;
    }

    float2 oo[5];
#pragma unroll
    for (int oc2 = 0; oc2 < 5; oc2++) oo[oc2] = make_float2(F3B[2 * oc2], F3B[2 * oc2 + 1]);
#pragma unroll 1
    for (int m2 = 0; m2 < 16; m2++) {
        float ax = F2B[2 * m2], ay = F2B[2 * m2 + 1];
        const float4* wv = F2W + m2 * 32;
#pragma unroll
        for (int ch2 = 0; ch2 < 32; ch2++) {
            float4 q = wv[ch2];
            ax = __builtin_fmaf(q.x, f[2 * ch2], ax); ax = __builtin_fmaf(q.z, f[2 * ch2 + 1], ax);
            ay = __builtin_fmaf(q.y, f[2 * ch2], ay); ay = __builtin_fmaf(q.w, f[2 * ch2 + 1], ay);
        }
        ax = fmaxf(ax, 0.f); ay = fmaxf(ay, 0.f);
#pragma unroll
        for (int oc2 = 0; oc2 < 5; oc2++) {
            float4 q = F3W[oc2 * 16 + m2];
            oo[oc2].x += q.x * ax + q.z * ay;
            oo[oc2].y += q.y * ax + q.w * ay;
        }
    }
    float* ob = out + (size_t)b * OUTC * NPIX + pix;
#pragma unroll
    for (int oc2 = 0; oc2 < 5; oc2++) {
        ob[(size_t)(2 * oc2) * NPIX]     = oo[oc2].x;
        ob[(size_t)(2 * oc2 + 1) * NPIX] = oo[oc2].y;
    }
}

extern "C" void kernel_launch(void* const* d_in, const int* in_sizes, int n_in,
                              void* d_out, int out_size, void* d_ws, size_t ws_size,
                              hipStream_t stream) {
    const float* x     = (const float*)d_in[0];
    const float* eattr = (const float*)d_in[3];
    const float* Wih0  = (const float*)d_in[4];
    const float* Whh0  = (const float*)d_in[5];
    const float* bih0  = (const float*)d_in[6];
    const float* bhh0  = (const float*)d_in[7];
    const float* Wih1  = (const float*)d_in[8];
    const float* Whh1  = (const float*)d_in[9];
    const float* bih1  = (const float*)d_in[10];
    const float* bhh1  = (const float*)d_in[11];
    const float* fc1w  = (const float*)d_in[12];
    const float* fc1b  = (const float*)d_in[13];
    const float* convw = (const float*)d_in[14];
    const float* convb = (const float*)d_in[15];
    const float* gparam= (const float*)d_in[16];
    const float* fc2w  = (const float*)d_in[17];
    const float* fc2b  = (const float*)d_in[18];
    const float* fc3w  = (const float*)d_in[19];
    const float* fc3b  = (const float*)d_in[20];

    float* P  = (float*)d_ws;
    float* FA = P + OFF_FEATS_A;
    float* FB = P + OFF_FEATS_B;

    prep_kernel<<<64, 256, 0, stream>>>(Wih0, Whh0, bih0, bhh0, Wih1, Whh1, bih1, bhh1,
                                        fc1w, fc1b, convw, convb, fc2w, fc2b, fc3w, fc3b,
                                        gparam, eattr, P);
    lstm_fc1_kernel<<<1024, 256, 0, stream>>>(x, P, FA);
    conv_fused_kernel<<<512, 256, 0, stream>>>(FA, FB, P, 0);
    conv_fused_kernel<<<512, 256, 0, stream>>>(FB, FA, P, 1);
    conv_fused_kernel<<<512, 256, 0, stream>>>(FA, FB, P, 2);
    conv_head_kernel<<<512, 256, 0, stream>>>(FB, P, (float*)d_out);
}

// Round 14
// 575.502 us; speedup vs baseline: 1.0151x; 1.0151x over previous
//
#include <hip/hip_runtime.h>
#include <hip/hip_bf16.h>

#define NPIX   65536
#define TT     5
#define CC     10
#define HH     32
#define WIDTH  64
#define KW     32
#define OUTC   10

// ---- workspace layout (float offsets) ----
#define OFF_L0I    0        // 1280  [c][j][g]
#define OFF_L0H    1280     // 4096  [k][j][g]
#define OFF_L1I    5376     // 4096
#define OFF_L1H    9472     // 4096
#define OFF_B0     13568    // 128   [j][g]
#define OFF_B1     13696    // 128
#define OFF_FC1W   13824    // 2048  [k][ch]
#define OFF_FC1B   15872    // 64
#define OFF_CWT2   16384    // 16384 [k][ci][co]  (straight copy of conv_w)
#define OFF_CB     32768    // 256
#define OFF_FC2W2  33024    // 2048  [m2][ch] float2
#define OFF_FC2B   35072    // 32
#define OFF_FC3W4  35104    // 320   [oc2][m2] float4
#define OFF_FC3B   35424    // 16
#define OFF_GW     35440    // 8
#define OFF_FEATS_A 36864
#define OFF_FEATS_B (36864 + 8388608)

#define STRAIGHT_ATTR_IDX (65025 * 3)

__device__ __forceinline__ float sigf(float x)  { return 1.0f / (1.0f + __expf(-x)); }
__device__ __forceinline__ float tanhf_(float x){ return 1.0f - 2.0f / (__expf(2.0f * x) + 1.0f); }

// ---------------- prep: pack params ----------------
__global__ __launch_bounds__(256, 1)
void prep_kernel(const float* Wih0, const float* Whh0,
                 const float* bih0, const float* bhh0,
                 const float* Wih1, const float* Whh1,
                 const float* bih1, const float* bhh1,
                 const float* fc1w, const float* fc1b,
                 const float* convw, const float* convb,
                 const float* fc2w, const float* fc2b,
                 const float* fc3w, const float* fc3b,
                 const float* gparam, const float* eattr,
                 float* P) {
    int tid = blockIdx.x * blockDim.x + threadIdx.x;
    int stride = gridDim.x * blockDim.x;
    // LSTM k-major: [k][j][g] <- W[(g*32+j)*K + k]
    for (int idx = tid; idx < 1280; idx += stride) {
        int g = idx & 3, j = (idx >> 2) & 31, c = idx >> 7;
        P[OFF_L0I + idx] = Wih0[(g * 32 + j) * 10 + c];
    }
    for (int idx = tid; idx < 4096; idx += stride) {
        int g = idx & 3, j = (idx >> 2) & 31, k = idx >> 7;
        P[OFF_L0H + idx] = Whh0[(g * 32 + j) * 32 + k];
        P[OFF_L1I + idx] = Wih1[(g * 32 + j) * 32 + k];
        P[OFF_L1H + idx] = Whh1[(g * 32 + j) * 32 + k];
    }
    for (int idx = tid; idx < 128; idx += stride) {
        int g = idx & 3, j = idx >> 2;
        P[OFF_B0 + idx] = bih0[g * 32 + j] + bhh0[g * 32 + j];
        P[OFF_B1 + idx] = bih1[g * 32 + j] + bhh1[g * 32 + j];
    }
    // fc1 k-major [k][ch]
    for (int idx = tid; idx < 2048; idx += stride) {
        int ch = idx & 63, k = idx >> 6;
        P[OFF_FC1W + idx] = fc1w[ch * 32 + k];
    }
    for (int i = tid; i < 64; i += stride) P[OFF_FC1B + i] = fc1b[i];
    // conv: straight copy, [k][ci][co] (convw native layout)
    for (int idx = tid; idx < 16384; idx += stride)
        P[OFF_CWT2 + idx] = convw[idx];
    for (int i = tid; i < 256; i += stride) P[OFF_CB + i] = convb[i];
    for (int idx = tid; idx < 2048; idx += stride) {
        int e = idx >> 1, h = idx & 1, m2 = e >> 6, ch = e & 63;
        P[OFF_FC2W2 + idx] = fc2w[(2 * m2 + h) * 64 + ch];
    }
    for (int i = tid; i < 32;  i += stride) P[OFF_FC2B + i] = fc2b[i];
    for (int idx = tid; idx < 320; idx += stride) {
        int q = idx & 3, e = idx >> 2, oc2 = e >> 4, m2 = e & 15;
        int oc = 2 * oc2 + (q & 1), m = 2 * m2 + (q >> 1);
        P[OFF_FC3W4 + idx] = fc3w[oc * 32 + m];
    }
    for (int i = tid; i < 10; i += stride) P[OFF_FC3B + i] = fc3b[i];
    for (int idx = tid; idx < 8; idx += stride) {
        int k = idx >> 1;
        float g = gparam[k];
        float denom = g * g + 1e-8f;
        float a = (idx & 1) ? eattr[0] : eattr[STRAIGHT_ATTR_IDX];
        P[OFF_GW + idx] = __expf(-(a * a) / denom);
    }
}

// ---------------- LSTM: 4-way wave j-split (R7 exact — ~329us floor) ----------------
// Settled R0-R13: the SGPR-weight v_fma stream costs ~4 issue-cyc/FMA and the
// cost is invariant under px-pairing (R13: weight shared across 2 FMAs, busy
// unchanged + spill) -> not a mov-amortization artifact; not AGPR-companion
// (R9); not launch_bounds-addressable (R8). Structural floor at HIP level.
#define ROW_ACC32(WBASE, SVAL) do {                                 \
    const float* wr_ = (WBASE); float sv_ = (SVAL);                 \
    _Pragma("unroll")                                               \
    for (int q_ = 0; q_ < 32; q_++)                                 \
        z[q_] = __builtin_fmaf(wr_[q_], sv_, z[q_]);                \
    } while (0)

__global__ __launch_bounds__(256, 1)
void lstm_fc1_kernel(const float* __restrict__ x,
                     const float* __restrict__ P,
                     float* __restrict__ feats) {
    __shared__ float H0[HH * 64];    // 8192 B  [j][lane]
    __shared__ float H1[HH * 64];    // 8192 B  (total 16384)

    int tid  = threadIdx.x;
    int w    = __builtin_amdgcn_readfirstlane(tid >> 6);  // wave id 0..3
    int lane = tid & 63;             // pixel column within block
    int jw   = w << 3;               // first owned unit (0,8,16,24)
    int w32  = w << 5;               // float offset into 128-wide gate rows

    int n = blockIdx.x * 64 + lane;
    int b = n >> 16;
    int pix = n & (NPIX - 1);
    const float* xb = x + (size_t)b * TT * CC * NPIX + pix;

    float c0[8], c1[8];
#pragma unroll
    for (int j = 0; j < 8; j++) {
        c0[j] = 0.f; c1[j] = 0.f;
        H0[(jw + j) * 64 + lane] = 0.f;
        H1[(jw + j) * 64 + lane] = 0.f;
    }
    __syncthreads();

#pragma unroll 1
    for (int t = 0; t < TT; t++) {
        float xcur[CC];
#pragma unroll
        for (int c = 0; c < CC; c++)
            xcur[c] = xb[(size_t)(t * CC + c) * NPIX];

        // ---- layer 0 ----
        {
            float z[32];             // [j_local*4+g], g=(i,f,g,o)
            const float* bb = P + OFF_B0 + w32;
#pragma unroll
            for (int q = 0; q < 32; q++) z[q] = bb[q];
#pragma unroll 1
            for (int c = 0; c < CC; c++)
                ROW_ACC32(P + OFF_L0I + c * 128 + w32, xcur[c]);
#pragma unroll 1
            for (int k = 0; k < HH; k++) {
                float hv = H0[k * 64 + lane];     // h0(t-1)
                ROW_ACC32(P + OFF_L0H + k * 128 + w32, hv);
            }
            __syncthreads();                      // all waves done reading old H0
#pragma unroll
            for (int j = 0; j < 8; j++) {
                float cn = sigf(z[4 * j + 1]) * c0[j]
                         + sigf(z[4 * j + 0]) * tanhf_(z[4 * j + 2]);
                c0[j] = cn;
                H0[(jw + j) * 64 + lane] = sigf(z[4 * j + 3]) * tanhf_(cn);
            }
            __syncthreads();                      // new H0 visible
        }

        // ---- layer 1 ----
        {
            float z[32];
            const float* bb = P + OFF_B1 + w32;
#pragma unroll
            for (int q = 0; q < 32; q++) z[q] = bb[q];
#pragma unroll 1
            for (int k = 0; k < HH; k++) {
                float hv = H0[k * 64 + lane];     // h0(t)
                ROW_ACC32(P + OFF_L1I + k * 128 + w32, hv);
            }
#pragma unroll 1
            for (int k = 0; k < HH; k++) {
                float hv = H1[k * 64 + lane];     // h1(t-1)
                ROW_ACC32(P + OFF_L1H + k * 128 + w32, hv);
            }
            __syncthreads();                      // all waves done reading old H1
#pragma unroll
            for (int j = 0; j < 8; j++) {
                float cn = sigf(z[4 * j + 1]) * c1[j]
                         + sigf(z[4 * j + 0]) * tanhf_(z[4 * j + 2]);
                c1[j] = cn;
                H1[(jw + j) * 64 + lane] = sigf(z[4 * j + 3]) * tanhf_(cn);
            }
            __syncthreads();                      // new H1 visible
        }
    }

    // ---- fc1 + relu: wave w computes ch in [16w, 16w+16) ----
    float f[16];
    {
        const float* fb1 = P + OFF_FC1B + (w << 4);
#pragma unroll
        for (int m = 0; m < 16; m++) f[m] = fb1[m];
    }
#pragma unroll 1
    for (int k = 0; k < HH; k++) {
        float hv = H1[k * 64 + lane];
        const float* wr = P + OFF_FC1W + k * 64 + (w << 4);
#pragma unroll
        for (int m = 0; m < 16; m++)
            f[m] = __builtin_fmaf(wr[m], hv, f[m]);
    }
    float* fob = feats + (size_t)b * WIDTH * NPIX + (size_t)(w * 16) * NPIX + pix;
#pragma unroll
    for (int m = 0; m < 16; m++)
        fob[(size_t)m * NPIX] = fmaxf(f[m], 0.f);
}

// ---------------- fused conv layer: quad-vectorized stencil + U-in-LDS GEMM ----------------
// R12 cut the GEMM's LDS traffic (4px/lane); R13's ci-unroll-2 kept (-6us).
// This round: the stencil was 576 scalar VMEM insts/lane (9 taps x 64 ch).
// Block = one image row (256 px, j=0..255). Thread covers quad q=tid&63
// (px 4q..4q+3) x 16 ch (chunk=tid>>6): per ch, 3 aligned float4 per row x 3
// rows = 9 loads for 4 px -> 144 VMEM/lane (4x fewer). Neighbor picks are
// compile-time float4 components; per-px expression shape preserved (same
// contraction -> same absmax). Out-of-range tap loads are x0 like before
// (workspace memory around FA/FB is valid).
__global__ __launch_bounds__(256, 1)
void conv_fused_kernel(const float* __restrict__ Fin, float* __restrict__ Fout,
                       const float* __restrict__ P, int k) {
    __shared__ float US[64 * 256];   // 65536 B  [ci][px]
    __shared__ float CW[64 * 64];    // 16384 B  [ci][co]

    int tid = threadIdx.x;
    {
        const float4* src = (const float4*)(P + OFF_CWT2 + k * 4096);
        float4* dst = (float4*)CW;
        for (int idx = tid; idx < 1024; idx += 256) dst[idx] = src[idx];
    }

    int q  = tid & 63;               // pixel quad within the row
    int ck = tid >> 6;               // channel chunk: ch in [16ck, 16ck+16)
    int n0 = blockIdx.x * 256;
    int b  = n0 >> 16;
    int pixbase = n0 & (NPIX - 1);   // row start (j = 0)
    int i  = pixbase >> 8;           // image row (uniform per block)

    float wstr = P[OFF_GW + 2 * k], wdiag = P[OFF_GW + 2 * k + 1];
    float fu  = (i > 0)   ? wstr  : 0.f;
    float fd  = (i < 255) ? wstr  : 0.f;
    float ulM = (i > 0)   ? wdiag : 0.f;     // interior up-diag
    float dlM = (i < 255) ? wdiag : 0.f;     // interior down-diag
    float fl0 = (q > 0)  ? wstr : 0.f;       // px0 left (j=4q)
    float fr3 = (q < 63) ? wstr : 0.f;       // px3 right (j=4q+3)
    float ul0 = (i > 0   && q > 0)  ? wdiag : 0.f;
    float dl0 = (i < 255 && q > 0)  ? wdiag : 0.f;
    float ur3 = (i > 0   && q < 63) ? wdiag : 0.f;
    float dr3 = (i < 255 && q < 63) ? wdiag : 0.f;

    const float* rowb = Fin + (size_t)b * WIDTH * NPIX + pixbase + 4 * q
                      + (size_t)(16 * ck) * NPIX;
    float4* US4w = (float4*)US;
#pragma unroll 1
    for (int cc = 0; cc < 16; cc++) {
        const float* rowc = rowb + (size_t)cc * NPIX;
        float4 cu  = *(const float4*)(rowc);
        float4 cp  = *(const float4*)(rowc - 4);
        float4 cn  = *(const float4*)(rowc + 4);
        float4 uu  = *(const float4*)(rowc - 256);
        float4 upq = *(const float4*)(rowc - 260);
        float4 unq = *(const float4*)(rowc - 252);
        float4 du  = *(const float4*)(rowc + 256);
        float4 dpq = *(const float4*)(rowc + 252);
        float4 dnq = *(const float4*)(rowc + 260);

        float4 v4;
        {   // p = 0 (j = 4q)
            float v = cu.x;
            v += fu * uu.x + fd * du.x + fl0 * cp.w + wstr * cu.y;
            v += ul0 * upq.w + ulM * uu.y + dl0 * dpq.w + dlM * du.y;
            v4.x = v;
        }
        {   // p = 1
            float v = cu.y;
            v += fu * uu.y + fd * du.y + wstr * cu.x + wstr * cu.z;
            v += ulM * uu.x + ulM * uu.z + dlM * du.x + dlM * du.z;
            v4.y = v;
        }
        {   // p = 2
            float v = cu.z;
            v += fu * uu.z + fd * du.z + wstr * cu.y + wstr * cu.w;
            v += ulM * uu.y + ulM * uu.w + dlM * du.y + dlM * du.w;
            v4.z = v;
        }
        {   // p = 3 (j = 4q+3)
            float v = cu.w;
            v += fu * uu.w + fd * du.w + wstr * cu.z + fr3 * cn.x;
            v += ulM * uu.z + ur3 * unq.x + dlM * du.z + dr3 * dnq.x;
            v4.w = v;
        }
        US4w[(16 * ck + cc) * 64 + q] = v4;
    }
    __syncthreads();

    int l = tid & 63;
    int ob16 = (tid >> 6) << 4;          // wave's first output channel
    float4 acc[16];
#pragma unroll
    for (int o = 0; o < 16; o++) {
        float bv = P[OFF_CB + k * 64 + ob16 + o];
        acc[o] = make_float4(bv, bv, bv, bv);
    }
    const float4* US4 = (const float4*)US;
#pragma unroll 2
    for (int ci = 0; ci < 64; ci++) {
        float4 u4 = US4[ci * 64 + l];
        const float4* wr4 = (const float4*)(CW + ci * 64 + ob16);
#pragma unroll
        for (int qq = 0; qq < 4; qq++) {
            float4 wq = wr4[qq];
            acc[4 * qq + 0].x = __builtin_fmaf(wq.x, u4.x, acc[4 * qq + 0].x);
            acc[4 * qq + 0].y = __builtin_fmaf(wq.x, u4.y, acc[4 * qq + 0].y);
            acc[4 * qq + 0].z = __builtin_fmaf(wq.x, u4.z, acc[4 * qq + 0].z);
            acc[4 * qq + 0].w = __builtin_fmaf(wq.x, u4.w, acc[4 * qq + 0].w);
            acc[4 * qq + 1].x = __builtin_fmaf(wq.y, u4.x, acc[4 * qq + 1].x);
            acc[4 * qq + 1].y = __builtin_fmaf(wq.y, u4.y, acc[4 * qq + 1].y);
            acc[4 * qq + 1].z = __builtin_fmaf(wq.y, u4.z, acc[4 * qq + 1].z);
            acc[4 * qq + 1].w = __builtin_fmaf(wq.y, u4.w, acc[4 * qq + 1].w);
            acc[4 * qq + 2].x = __builtin_fmaf(wq.z, u4.x, acc[4 * qq + 2].x);
            acc[4 * qq + 2].y = __builtin_fmaf(wq.z, u4.y, acc[4 * qq + 2].y);
            acc[4 * qq + 2].z = __builtin_fmaf(wq.z, u4.z, acc[4 * qq + 2].z);
            acc[4 * qq + 2].w = __builtin_fmaf(wq.z, u4.w, acc[4 * qq + 2].w);
            acc[4 * qq + 3].x = __builtin_fmaf(wq.w, u4.x, acc[4 * qq + 3].x);
            acc[4 * qq + 3].y = __builtin_fmaf(wq.w, u4.y, acc[4 * qq + 3].y);
            acc[4 * qq + 3].z = __builtin_fmaf(wq.w, u4.z, acc[4 * qq + 3].z);
            acc[4 * qq + 3].w = __builtin_fmaf(wq.w, u4.w, acc[4 * qq + 3].w);
        }
    }

    int pn = blockIdx.x * 256 + 4 * l;   // first of this lane's 4 pixels
    int pb = pn >> 16;
    int ppix = pn & (NPIX - 1);
    float* ob = Fout + (size_t)pb * WIDTH * NPIX + ppix;
#pragma unroll
    for (int o = 0; o < 16; o++) {
        float4 r;
        r.x = fmaxf(acc[o].x, 0.f); r.y = fmaxf(acc[o].y, 0.f);
        r.z = fmaxf(acc[o].z, 0.f); r.w = fmaxf(acc[o].w, 0.f);
        *(float4*)(ob + (size_t)(ob16 + o) * NPIX) = r;
    }
}

// ---------------- last conv (no relu) + fc2/fc3 head (R12 exact) ----------------
__global__ __launch_bounds__(256, 1)
void conv_head_kernel(const float* __restrict__ Fin, const float* __restrict__ P,
                      float* __restrict__ out) {
    const int k = 3;
    __shared__ float4 CW3[1024];
    __shared__ float  CB3[64];
    __shared__ float4 F2W[512];
    __shared__ float  F2B[32];
    __shared__ float4 F3W[80];
    __shared__ float  F3B[12];
    {
        const float* wsrc = P + OFF_CWT2 + k * 4096;   // [ci][co]
        for (int idx = threadIdx.x; idx < 1024; idx += 256) {
            int co2 = idx >> 5, ci2 = idx & 31;
            CW3[idx] = make_float4(wsrc[(2 * ci2) * 64 + 2 * co2],
                                   wsrc[(2 * ci2) * 64 + 2 * co2 + 1],
                                   wsrc[(2 * ci2 + 1) * 64 + 2 * co2],
                                   wsrc[(2 * ci2 + 1) * 64 + 2 * co2 + 1]);
        }
        const float4* s2 = (const float4*)(P + OFF_FC2W2);
        for (int i = threadIdx.x; i < 512; i += 256) F2W[i] = s2[i];
        const float4* s3 = (const float4*)(P + OFF_FC3W4);
        if (threadIdx.x < 80) F3W[threadIdx.x] = s3[threadIdx.x];
        if (threadIdx.x < 64) CB3[threadIdx.x] = P[OFF_CB + k * 64 + threadIdx.x];
        if (threadIdx.x < 32) F2B[threadIdx.x] = P[OFF_FC2B + threadIdx.x];
        if (threadIdx.x < 10) F3B[threadIdx.x] = P[OFF_FC3B + threadIdx.x];
    }
    __syncthreads();

    int n = blockIdx.x * 256 + threadIdx.x;
    int b = n >> 16;
    int pix = n & (NPIX - 1);
    int i = pix >> 8, j = pix & 255;
    float wstr = P[OFF_GW + 2 * k], wdiag = P[OFF_GW + 2 * k + 1];
    float fu = (i > 0) ? wstr : 0.f, fd = (i < 255) ? wstr : 0.f;
    float fl = (j > 0) ? wstr : 0.f, fr = (j < 255) ? wstr : 0.f;
    float ful = (i > 0 && j > 0) ? wdiag : 0.f, fur = (i > 0 && j < 255) ? wdiag : 0.f;
    float fdl = (i < 255 && j > 0) ? wdiag : 0.f, fdr = (i < 255 && j < 255) ? wdiag : 0.f;

    const float* fb = Fin + (size_t)b * WIDTH * NPIX + pix;
    float u[WIDTH];
#pragma unroll
    for (int ch = 0; ch < WIDTH; ch++) {
        const float* yc = fb + (size_t)ch * NPIX;
        float v = yc[0];
        v += fu * yc[-256] + fd * yc[256] + fl * yc[-1] + fr * yc[1];
        v += ful * yc[-257] + fur * yc[-255] + fdl * yc[255] + fdr * yc[257];
        u[ch] = v;
    }

    float f[WIDTH];
#pragma unroll
    for (int co2 = 0; co2 < 32; co2++) {
        float ax = CB3[2 * co2], ay = CB3[2 * co2 + 1];
        const float4* wv = CW3 + co2 * 32;
#pragma unroll
        for (int ci2 = 0; ci2 < 32; ci2++) {
            float4 q = wv[ci2];
            float a0 = u[2 * ci2], a1 = u[2 * ci2 + 1];
            ax = __builtin_fmaf(q.x, a0, ax); ax = __builtin_fmaf(q.z, a1, ax);
            ay = __builtin_fmaf(q.y, a0, ay); ay = __builtin_fmaf(q.w, a1, ay);
        }
        f[2 * co2] = ax; f[2 * co2 + 1] = ay;
    }

    float2 oo[5];
#pragma unroll
    for (int oc2 = 0; oc2 < 5; oc2++) oo[oc2] = make_float2(F3B[2 * oc2], F3B[2 * oc2 + 1]);
#pragma unroll 1
    for (int m2 = 0; m2 < 16; m2++) {
        float ax = F2B[2 * m2], ay = F2B[2 * m2 + 1];
        const float4* wv = F2W + m2 * 32;
#pragma unroll
        for (int ch2 = 0; ch2 < 32; ch2++) {
            float4 q = wv[ch2];
            ax = __builtin_fmaf(q.x, f[2 * ch2], ax); ax = __builtin_fmaf(q.z, f[2 * ch2 + 1], ax);
            ay = __builtin_fmaf(q.y, f[2 * ch2], ay); ay = __builtin_fmaf(q.w, f[2 * ch2 + 1], ay);
        }
        ax = fmaxf(ax, 0.f); ay = fmaxf(ay, 0.f);
#pragma unroll
        for (int oc2 = 0; oc2 < 5; oc2++) {
            float4 q = F3W[oc2 * 16 + m2];
            oo[oc2].x += q.x * ax + q.z * ay;
            oo[oc2].y += q.y * ax + q.w * ay;
        }
    }
    float* ob = out + (size_t)b * OUTC * NPIX + pix;
#pragma unroll
    for (int oc2 = 0; oc2 < 5; oc2++) {
        ob[(size_t)(2 * oc2) * NPIX]     = oo[oc2].x;
        ob[(size_t)(2 * oc2 + 1) * NPIX] = oo[oc2].y;
    }
}

extern "C" void kernel_launch(void* const* d_in, const int* in_sizes, int n_in,
                              void* d_out, int out_size, void* d_ws, size_t ws_size,
                              hipStream_t stream) {
    const float* x     = (const float*)d_in[0];
    const float* eattr = (const float*)d_in[3];
    const float* Wih0  = (const float*)d_in[4];
    const float* Whh0  = (const float*)d_in[5];
    const float* bih0  = (const float*)d_in[6];
    const float* bhh0  = (const float*)d_in[7];
    const float* Wih1  = (const float*)d_in[8];
    const float* Whh1  = (const float*)d_in[9];
    const float* bih1  = (const float*)d_in[10];
    const float* bhh1  = (const float*)d_in[11];
    const float* fc1w  = (const float*)d_in[12];
    const float* fc1b  = (const float*)d_in[13];
    const float* convw = (const float*)d_in[14];
    const float* convb = (const float*)d_in[15];
    const float* gparam= (const float*)d_in[16];
    const float* fc2w  = (const float*)d_in[17];
    const float* fc2b  = (const float*)d_in[18];
    const float* fc3w  = (const float*)d_in[19];
    const float* fc3b  = (const float*)d_in[20];

    float* P  = (float*)d_ws;
    float* FA = P + OFF_FEATS_A;
    float* FB = P + OFF_FEATS_B;

    prep_kernel<<<64, 256, 0, stream>>>(Wih0, Whh0, bih0, bhh0, Wih1, Whh1, bih1, bhh1,
                                        fc1w, fc1b, convw, convb, fc2w, fc2b, fc3w, fc3b,
                                        gparam, eattr, P);
    lstm_fc1_kernel<<<2048, 256, 0, stream>>>(x, P, FA);
    conv_fused_kernel<<<512, 256, 0, stream>>>(FA, FB, P, 0);
    conv_fused_kernel<<<512, 256, 0, stream>>>(FB, FA, P, 1);
    conv_fused_kernel<<<512, 256, 0, stream>>>(FA, FB, P, 2);
    conv_head_kernel<<<512, 256, 0, stream>>>(FB, P, (float*)d_out);
}

// Round 15
// 563.548 us; speedup vs baseline: 1.0366x; 1.0212x over previous
//
#include <hip/hip_runtime.h>
#include <hip/hip_bf16.h>

#define NPIX   65536
#define TT     5
#define CC     10
#define HH     32
#define WIDTH  64
#define KW     32
#define OUTC   10

// ---- workspace layout (float offsets) ----
#define OFF_L0I    0        // 1280  [c][j][g]
#define OFF_L0H    1280     // 4096  [k][j][g]
#define OFF_L1I    5376     // 4096
#define OFF_L1H    9472     // 4096
#define OFF_B0     13568    // 128   [j][g]
#define OFF_B1     13696    // 128
#define OFF_FC1W   13824    // 2048  [k][ch]
#define OFF_FC1B   15872    // 64
#define OFF_CWT2   16384    // 16384 [k][ci][co]  (straight copy of conv_w)
#define OFF_CB     32768    // 256
#define OFF_FC2W2  33024    // 2048  [m2][ch] float2
#define OFF_FC2B   35072    // 32
#define OFF_FC3W4  35104    // 320   [oc2][m2] float4
#define OFF_FC3B   35424    // 16
#define OFF_GW     35440    // 8
#define OFF_FEATS_A 36864
#define OFF_FEATS_B (36864 + 8388608)

#define STRAIGHT_ATTR_IDX (65025 * 3)

__device__ __forceinline__ float sigf(float x)  { return 1.0f / (1.0f + __expf(-x)); }
__device__ __forceinline__ float tanhf_(float x){ return 1.0f - 2.0f / (__expf(2.0f * x) + 1.0f); }

// ---------------- prep: pack params ----------------
__global__ __launch_bounds__(256, 1)
void prep_kernel(const float* Wih0, const float* Whh0,
                 const float* bih0, const float* bhh0,
                 const float* Wih1, const float* Whh1,
                 const float* bih1, const float* bhh1,
                 const float* fc1w, const float* fc1b,
                 const float* convw, const float* convb,
                 const float* fc2w, const float* fc2b,
                 const float* fc3w, const float* fc3b,
                 const float* gparam, const float* eattr,
                 float* P) {
    int tid = blockIdx.x * blockDim.x + threadIdx.x;
    int stride = gridDim.x * blockDim.x;
    // LSTM k-major: [k][j][g] <- W[(g*32+j)*K + k]
    for (int idx = tid; idx < 1280; idx += stride) {
        int g = idx & 3, j = (idx >> 2) & 31, c = idx >> 7;
        P[OFF_L0I + idx] = Wih0[(g * 32 + j) * 10 + c];
    }
    for (int idx = tid; idx < 4096; idx += stride) {
        int g = idx & 3, j = (idx >> 2) & 31, k = idx >> 7;
        P[OFF_L0H + idx] = Whh0[(g * 32 + j) * 32 + k];
        P[OFF_L1I + idx] = Wih1[(g * 32 + j) * 32 + k];
        P[OFF_L1H + idx] = Whh1[(g * 32 + j) * 32 + k];
    }
    for (int idx = tid; idx < 128; idx += stride) {
        int g = idx & 3, j = idx >> 2;
        P[OFF_B0 + idx] = bih0[g * 32 + j] + bhh0[g * 32 + j];
        P[OFF_B1 + idx] = bih1[g * 32 + j] + bhh1[g * 32 + j];
    }
    // fc1 k-major [k][ch]
    for (int idx = tid; idx < 2048; idx += stride) {
        int ch = idx & 63, k = idx >> 6;
        P[OFF_FC1W + idx] = fc1w[ch * 32 + k];
    }
    for (int i = tid; i < 64; i += stride) P[OFF_FC1B + i] = fc1b[i];
    // conv: straight copy, [k][ci][co] (convw native layout)
    for (int idx = tid; idx < 16384; idx += stride)
        P[OFF_CWT2 + idx] = convw[idx];
    for (int i = tid; i < 256; i += stride) P[OFF_CB + i] = convb[i];
    for (int idx = tid; idx < 2048; idx += stride) {
        int e = idx >> 1, h = idx & 1, m2 = e >> 6, ch = e & 63;
        P[OFF_FC2W2 + idx] = fc2w[(2 * m2 + h) * 64 + ch];
    }
    for (int i = tid; i < 32;  i += stride) P[OFF_FC2B + i] = fc2b[i];
    for (int idx = tid; idx < 320; idx += stride) {
        int q = idx & 3, e = idx >> 2, oc2 = e >> 4, m2 = e & 15;
        int oc = 2 * oc2 + (q & 1), m = 2 * m2 + (q >> 1);
        P[OFF_FC3W4 + idx] = fc3w[oc * 32 + m];
    }
    for (int i = tid; i < 10; i += stride) P[OFF_FC3B + i] = fc3b[i];
    for (int idx = tid; idx < 8; idx += stride) {
        int k = idx >> 1;
        float g = gparam[k];
        float denom = g * g + 1e-8f;
        float a = (idx & 1) ? eattr[0] : eattr[STRAIGHT_ATTR_IDX];
        P[OFF_GW + idx] = __expf(-(a * a) / denom);
    }
}

// ---------------- LSTM: 4-way wave j-split (R7 exact — ~327us floor) ----------------
// Settled R0-R13: the SGPR-weight v_fma stream costs ~4 issue-cyc/FMA; the
// cost is invariant under px-pairing (R13: weight shared across 2 FMAs, busy
// unchanged + spill), not an AGPR-companion tax (R9: forced arch-VGPR accs,
// busy unchanged), not launch_bounds-addressable (R8). Structural floor at
// HIP source level.
#define ROW_ACC32(WBASE, SVAL) do {                                 \
    const float* wr_ = (WBASE); float sv_ = (SVAL);                 \
    _Pragma("unroll")                                               \
    for (int q_ = 0; q_ < 32; q_++)                                 \
        z[q_] = __builtin_fmaf(wr_[q_], sv_, z[q_]);                \
    } while (0)

__global__ __launch_bounds__(256, 1)
void lstm_fc1_kernel(const float* __restrict__ x,
                     const float* __restrict__ P,
                     float* __restrict__ feats) {
    __shared__ float H0[HH * 64];    // 8192 B  [j][lane]
    __shared__ float H1[HH * 64];    // 8192 B  (total 16384)

    int tid  = threadIdx.x;
    int w    = __builtin_amdgcn_readfirstlane(tid >> 6);  // wave id 0..3
    int lane = tid & 63;             // pixel column within block
    int jw   = w << 3;               // first owned unit (0,8,16,24)
    int w32  = w << 5;               // float offset into 128-wide gate rows

    int n = blockIdx.x * 64 + lane;
    int b = n >> 16;
    int pix = n & (NPIX - 1);
    const float* xb = x + (size_t)b * TT * CC * NPIX + pix;

    float c0[8], c1[8];
#pragma unroll
    for (int j = 0; j < 8; j++) {
        c0[j] = 0.f; c1[j] = 0.f;
        H0[(jw + j) * 64 + lane] = 0.f;
        H1[(jw + j) * 64 + lane] = 0.f;
    }
    __syncthreads();

#pragma unroll 1
    for (int t = 0; t < TT; t++) {
        float xcur[CC];
#pragma unroll
        for (int c = 0; c < CC; c++)
            xcur[c] = xb[(size_t)(t * CC + c) * NPIX];

        // ---- layer 0 ----
        {
            float z[32];             // [j_local*4+g], g=(i,f,g,o)
            const float* bb = P + OFF_B0 + w32;
#pragma unroll
            for (int q = 0; q < 32; q++) z[q] = bb[q];
#pragma unroll 1
            for (int c = 0; c < CC; c++)
                ROW_ACC32(P + OFF_L0I + c * 128 + w32, xcur[c]);
#pragma unroll 1
            for (int k = 0; k < HH; k++) {
                float hv = H0[k * 64 + lane];     // h0(t-1)
                ROW_ACC32(P + OFF_L0H + k * 128 + w32, hv);
            }
            __syncthreads();                      // all waves done reading old H0
#pragma unroll
            for (int j = 0; j < 8; j++) {
                float cn = sigf(z[4 * j + 1]) * c0[j]
                         + sigf(z[4 * j + 0]) * tanhf_(z[4 * j + 2]);
                c0[j] = cn;
                H0[(jw + j) * 64 + lane] = sigf(z[4 * j + 3]) * tanhf_(cn);
            }
            __syncthreads();                      // new H0 visible
        }

        // ---- layer 1 ----
        {
            float z[32];
            const float* bb = P + OFF_B1 + w32;
#pragma unroll
            for (int q = 0; q < 32; q++) z[q] = bb[q];
#pragma unroll 1
            for (int k = 0; k < HH; k++) {
                float hv = H0[k * 64 + lane];     // h0(t)
                ROW_ACC32(P + OFF_L1I + k * 128 + w32, hv);
            }
#pragma unroll 1
            for (int k = 0; k < HH; k++) {
                float hv = H1[k * 64 + lane];     // h1(t-1)
                ROW_ACC32(P + OFF_L1H + k * 128 + w32, hv);
            }
            __syncthreads();                      // all waves done reading old H1
#pragma unroll
            for (int j = 0; j < 8; j++) {
                float cn = sigf(z[4 * j + 1]) * c1[j]
                         + sigf(z[4 * j + 0]) * tanhf_(z[4 * j + 2]);
                c1[j] = cn;
                H1[(jw + j) * 64 + lane] = sigf(z[4 * j + 3]) * tanhf_(cn);
            }
            __syncthreads();                      // new H1 visible
        }
    }

    // ---- fc1 + relu: wave w computes ch in [16w, 16w+16) ----
    float f[16];
    {
        const float* fb1 = P + OFF_FC1B + (w << 4);
#pragma unroll
        for (int m = 0; m < 16; m++) f[m] = fb1[m];
    }
#pragma unroll 1
    for (int k = 0; k < HH; k++) {
        float hv = H1[k * 64 + lane];
        const float* wr = P + OFF_FC1W + k * 64 + (w << 4);
#pragma unroll
        for (int m = 0; m < 16; m++)
            f[m] = __builtin_fmaf(wr[m], hv, f[m]);
    }
    float* fob = feats + (size_t)b * WIDTH * NPIX + (size_t)(w * 16) * NPIX + pix;
#pragma unroll
    for (int m = 0; m < 16; m++)
        fob[(size_t)m * NPIX] = fmaxf(f[m], 0.f);
}

// ---------------- fused conv layer: U-in-LDS, 4 px x 16 outs per lane (R13 exact) ----------------
// R12 structure (-25us over R8 by amortizing W reads over 4 px/lane) +
// R13 ci-unroll-2 (-6us, pipelines the U/W ds_reads). R14's quad-vectorized
// stencil REGRESSED (+15us: overlapping float4 taps ~3x bytes, float4 US
// writes 8-way bank serialization) -> scalar per-pixel stencil restored.
__global__ __launch_bounds__(256, 1)
void conv_fused_kernel(const float* __restrict__ Fin, float* __restrict__ Fout,
                       const float* __restrict__ P, int k) {
    __shared__ float US[64 * 256];   // 65536 B  [ci][px]
    __shared__ float CW[64 * 64];    // 16384 B  [ci][co]

    int tid = threadIdx.x;
    {
        const float4* src = (const float4*)(P + OFF_CWT2 + k * 4096);
        float4* dst = (float4*)CW;
        for (int idx = tid; idx < 1024; idx += 256) dst[idx] = src[idx];
    }

    int n = blockIdx.x * 256 + tid;
    int b = n >> 16;
    int pix = n & (NPIX - 1);
    int i = pix >> 8, j = pix & 255;
    float wstr = P[OFF_GW + 2 * k], wdiag = P[OFF_GW + 2 * k + 1];
    float fu = (i > 0) ? wstr : 0.f, fd = (i < 255) ? wstr : 0.f;
    float fl = (j > 0) ? wstr : 0.f, fr = (j < 255) ? wstr : 0.f;
    float ful = (i > 0 && j > 0) ? wdiag : 0.f, fur = (i > 0 && j < 255) ? wdiag : 0.f;
    float fdl = (i < 255 && j > 0) ? wdiag : 0.f, fdr = (i < 255 && j < 255) ? wdiag : 0.f;

    const float* fb = Fin + (size_t)b * WIDTH * NPIX + pix;
#pragma unroll
    for (int ch = 0; ch < WIDTH; ch++) {
        const float* yc = fb + (size_t)ch * NPIX;
        float v = yc[0];
        v += fu * yc[-256] + fd * yc[256] + fl * yc[-1] + fr * yc[1];
        v += ful * yc[-257] + fur * yc[-255] + fdl * yc[255] + fdr * yc[257];
        US[ch * 256 + tid] = v;
    }
    __syncthreads();

    int l = tid & 63;
    int ob16 = (tid >> 6) << 4;          // wave's first output channel
    float4 acc[16];
#pragma unroll
    for (int o = 0; o < 16; o++) {
        float bv = P[OFF_CB + k * 64 + ob16 + o];
        acc[o] = make_float4(bv, bv, bv, bv);
    }
    const float4* US4 = (const float4*)US;
#pragma unroll 2
    for (int ci = 0; ci < 64; ci++) {
        float4 u4 = US4[ci * 64 + l];
        const float4* wr4 = (const float4*)(CW + ci * 64 + ob16);
#pragma unroll
        for (int q = 0; q < 4; q++) {
            float4 wq = wr4[q];
            acc[4 * q + 0].x = __builtin_fmaf(wq.x, u4.x, acc[4 * q + 0].x);
            acc[4 * q + 0].y = __builtin_fmaf(wq.x, u4.y, acc[4 * q + 0].y);
            acc[4 * q + 0].z = __builtin_fmaf(wq.x, u4.z, acc[4 * q + 0].z);
            acc[4 * q + 0].w = __builtin_fmaf(wq.x, u4.w, acc[4 * q + 0].w);
            acc[4 * q + 1].x = __builtin_fmaf(wq.y, u4.x, acc[4 * q + 1].x);
            acc[4 * q + 1].y = __builtin_fmaf(wq.y, u4.y, acc[4 * q + 1].y);
            acc[4 * q + 1].z = __builtin_fmaf(wq.y, u4.z, acc[4 * q + 1].z);
            acc[4 * q + 1].w = __builtin_fmaf(wq.y, u4.w, acc[4 * q + 1].w);
            acc[4 * q + 2].x = __builtin_fmaf(wq.z, u4.x, acc[4 * q + 2].x);
            acc[4 * q + 2].y = __builtin_fmaf(wq.z, u4.y, acc[4 * q + 2].y);
            acc[4 * q + 2].z = __builtin_fmaf(wq.z, u4.z, acc[4 * q + 2].z);
            acc[4 * q + 2].w = __builtin_fmaf(wq.z, u4.w, acc[4 * q + 2].w);
            acc[4 * q + 3].x = __builtin_fmaf(wq.w, u4.x, acc[4 * q + 3].x);
            acc[4 * q + 3].y = __builtin_fmaf(wq.w, u4.y, acc[4 * q + 3].y);
            acc[4 * q + 3].z = __builtin_fmaf(wq.w, u4.z, acc[4 * q + 3].z);
            acc[4 * q + 3].w = __builtin_fmaf(wq.w, u4.w, acc[4 * q + 3].w);
        }
    }

    int pn = blockIdx.x * 256 + 4 * l;   // first of this lane's 4 pixels
    int pb = pn >> 16;
    int ppix = pn & (NPIX - 1);
    float* ob = Fout + (size_t)pb * WIDTH * NPIX + ppix;
#pragma unroll
    for (int o = 0; o < 16; o++) {
        float4 r;
        r.x = fmaxf(acc[o].x, 0.f); r.y = fmaxf(acc[o].y, 0.f);
        r.z = fmaxf(acc[o].z, 0.f); r.w = fmaxf(acc[o].w, 0.f);
        *(float4*)(ob + (size_t)(ob16 + o) * NPIX) = r;
    }
}

// ---------------- last conv (no relu) + fc2/fc3 head (R12 exact) ----------------
__global__ __launch_bounds__(256, 1)
void conv_head_kernel(const float* __restrict__ Fin, const float* __restrict__ P,
                      float* __restrict__ out) {
    const int k = 3;
    __shared__ float4 CW3[1024];
    __shared__ float  CB3[64];
    __shared__ float4 F2W[512];
    __shared__ float  F2B[32];
    __shared__ float4 F3W[80];
    __shared__ float  F3B[12];
    {
        const float* wsrc = P + OFF_CWT2 + k * 4096;   // [ci][co]
        for (int idx = threadIdx.x; idx < 1024; idx += 256) {
            int co2 = idx >> 5, ci2 = idx & 31;
            CW3[idx] = make_float4(wsrc[(2 * ci2) * 64 + 2 * co2],
                                   wsrc[(2 * ci2) * 64 + 2 * co2 + 1],
                                   wsrc[(2 * ci2 + 1) * 64 + 2 * co2],
                                   wsrc[(2 * ci2 + 1) * 64 + 2 * co2 + 1]);
        }
        const float4* s2 = (const float4*)(P + OFF_FC2W2);
        for (int i = threadIdx.x; i < 512; i += 256) F2W[i] = s2[i];
        const float4* s3 = (const float4*)(P + OFF_FC3W4);
        if (threadIdx.x < 80) F3W[threadIdx.x] = s3[threadIdx.x];
        if (threadIdx.x < 64) CB3[threadIdx.x] = P[OFF_CB + k * 64 + threadIdx.x];
        if (threadIdx.x < 32) F2B[threadIdx.x] = P[OFF_FC2B + threadIdx.x];
        if (threadIdx.x < 10) F3B[threadIdx.x] = P[OFF_FC3B + threadIdx.x];
    }
    __syncthreads();

    int n = blockIdx.x * 256 + threadIdx.x;
    int b = n >> 16;
    int pix = n & (NPIX - 1);
    int i = pix >> 8, j = pix & 255;
    float wstr = P[OFF_GW + 2 * k], wdiag = P[OFF_GW + 2 * k + 1];
    float fu = (i > 0) ? wstr : 0.f, fd = (i < 255) ? wstr : 0.f;
    float fl = (j > 0) ? wstr : 0.f, fr = (j < 255) ? wstr : 0.f;
    float ful = (i > 0 && j > 0) ? wdiag : 0.f, fur = (i > 0 && j < 255) ? wdiag : 0.f;
    float fdl = (i < 255 && j > 0) ? wdiag : 0.f, fdr = (i < 255 && j < 255) ? wdiag : 0.f;

    const float* fb = Fin + (size_t)b * WIDTH * NPIX + pix;
    float u[WIDTH];
#pragma unroll
    for (int ch = 0; ch < WIDTH; ch++) {
        const float* yc = fb + (size_t)ch * NPIX;
        float v = yc[0];
        v += fu * yc[-256] + fd * yc[256] + fl * yc[-1] + fr * yc[1];
        v += ful * yc[-257] + fur * yc[-255] + fdl * yc[255] + fdr * yc[257];
        u[ch] = v;
    }

    float f[WIDTH];
#pragma unroll
    for (int co2 = 0; co2 < 32; co2++) {
        float ax = CB3[2 * co2], ay = CB3[2 * co2 + 1];
        const float4* wv = CW3 + co2 * 32;
#pragma unroll
        for (int ci2 = 0; ci2 < 32; ci2++) {
            float4 q = wv[ci2];
            float a0 = u[2 * ci2], a1 = u[2 * ci2 + 1];
            ax = __builtin_fmaf(q.x, a0, ax); ax = __builtin_fmaf(q.z, a1, ax);
            ay = __builtin_fmaf(q.y, a0, ay); ay = __builtin_fmaf(q.w, a1, ay);
        }
        f[2 * co2] = ax; f[2 * co2 + 1] = ay;
    }

    float2 oo[5];
#pragma unroll
    for (int oc2 = 0; oc2 < 5; oc2++) oo[oc2] = make_float2(F3B[2 * oc2], F3B[2 * oc2 + 1]);
#pragma unroll 1
    for (int m2 = 0; m2 < 16; m2++) {
        float ax = F2B[2 * m2], ay = F2B[2 * m2 + 1];
        const float4* wv = F2W + m2 * 32;
#pragma unroll
        for (int ch2 = 0; ch2 < 32; ch2++) {
            float4 q = wv[ch2];
            ax = __builtin_fmaf(q.x, f[2 * ch2], ax); ax = __builtin_fmaf(q.z, f[2 * ch2 + 1], ax);
            ay = __builtin_fmaf(q.y, f[2 * ch2], ay); ay = __builtin_fmaf(q.w, f[2 * ch2 + 1], ay);
        }
        ax = fmaxf(ax, 0.f); ay = fmaxf(ay, 0.f);
#pragma unroll
        for (int oc2 = 0; oc2 < 5; oc2++) {
            float4 q = F3W[oc2 * 16 + m2];
            oo[oc2].x += q.x * ax + q.z * ay;
            oo[oc2].y += q.y * ax + q.w * ay;
        }
    }
    float* ob = out + (size_t)b * OUTC * NPIX + pix;
#pragma unroll
    for (int oc2 = 0; oc2 < 5; oc2++) {
        ob[(size_t)(2 * oc2) * NPIX]     = oo[oc2].x;
        ob[(size_t)(2 * oc2 + 1) * NPIX] = oo[oc2].y;
    }
}

extern "C" void kernel_launch(void* const* d_in, const int* in_sizes, int n_in,
                              void* d_out, int out_size, void* d_ws, size_t ws_size,
                              hipStream_t stream) {
    const float* x     = (const float*)d_in[0];
    const float* eattr = (const float*)d_in[3];
    const float* Wih0  = (const float*)d_in[4];
    const float* Whh0  = (const float*)d_in[5];
    const float* bih0  = (const float*)d_in[6];
    const float* bhh0  = (const float*)d_in[7];
    const float* Wih1  = (const float*)d_in[8];
    const float* Whh1  = (const float*)d_in[9];
    const float* bih1  = (const float*)d_in[10];
    const float* bhh1  = (const float*)d_in[11];
    const float* fc1w  = (const float*)d_in[12];
    const float* fc1b  = (const float*)d_in[13];
    const float* convw = (const float*)d_in[14];
    const float* convb = (const float*)d_in[15];
    const float* gparam= (const float*)d_in[16];
    const float* fc2w  = (const float*)d_in[17];
    const float* fc2b  = (const float*)d_in[18];
    const float* fc3w  = (const float*)d_in[19];
    const float* fc3b  = (const float*)d_in[20];

    float* P  = (float*)d_ws;
    float* FA = P + OFF_FEATS_A;
    float* FB = P + OFF_FEATS_B;

    prep_kernel<<<64, 256, 0, stream>>>(Wih0, Whh0, bih0, bhh0, Wih1, Whh1, bih1, bhh1,
                                        fc1w, fc1b, convw, convb, fc2w, fc2b, fc3w, fc3b,
                                        gparam, eattr, P);
    lstm_fc1_kernel<<<2048, 256, 0, stream>>>(x, P, FA);
    conv_fused_kernel<<<512, 256, 0, stream>>>(FA, FB, P, 0);
    conv_fused_kernel<<<512, 256, 0, stream>>>(FB, FA, P, 1);
    conv_fused_kernel<<<512, 256, 0, stream>>>(FA, FB, P, 2);
    conv_head_kernel<<<512, 256, 0, stream>>>(FB, P, (float*)d_out);
}

// Round 16
// 529.365 us; speedup vs baseline: 1.1035x; 1.0646x over previous
//
#include <hip/hip_runtime.h>
#include <hip/hip_bf16.h>

#define NPIX   65536
#define TT     5
#define CC     10
#define HH     32
#define WIDTH  64
#define KW     32
#define OUTC   10

// ---- workspace layout (float offsets) ----
#define OFF_L0I    0        // 1280  [c][j][g]
#define OFF_L0H    1280     // 4096  [k][j][g]
#define OFF_L1I    5376     // 4096
#define OFF_L1H    9472     // 4096
#define OFF_B0     13568    // 128   [j][g]
#define OFF_B1     13696    // 128
#define OFF_FC1W   13824    // 2048  [k][ch]
#define OFF_FC1B   15872    // 64
#define OFF_CWT2   16384    // 16384 [k][ci][co]  (straight copy of conv_w)
#define OFF_CB     32768    // 256
#define OFF_FC2W2  33024    // 2048  [m2][ch] float2
#define OFF_FC2B   35072    // 32
#define OFF_FC3W4  35104    // 320   [oc2][m2] float4
#define OFF_FC3B   35424    // 16
#define OFF_GW     35440    // 8
#define OFF_FEATS_A 36864
#define OFF_FEATS_B (36864 + 8388608)

#define STRAIGHT_ATTR_IDX (65025 * 3)

__device__ __forceinline__ float sigf(float x)  { return 1.0f / (1.0f + __expf(-x)); }
__device__ __forceinline__ float tanhf_(float x){ return 1.0f - 2.0f / (__expf(2.0f * x) + 1.0f); }

// ---------------- prep: pack params ----------------
__global__ __launch_bounds__(256, 1)
void prep_kernel(const float* Wih0, const float* Whh0,
                 const float* bih0, const float* bhh0,
                 const float* Wih1, const float* Whh1,
                 const float* bih1, const float* bhh1,
                 const float* fc1w, const float* fc1b,
                 const float* convw, const float* convb,
                 const float* fc2w, const float* fc2b,
                 const float* fc3w, const float* fc3b,
                 const float* gparam, const float* eattr,
                 float* P) {
    int tid = blockIdx.x * blockDim.x + threadIdx.x;
    int stride = gridDim.x * blockDim.x;
    // LSTM k-major: [k][j][g] <- W[(g*32+j)*K + k]
    for (int idx = tid; idx < 1280; idx += stride) {
        int g = idx & 3, j = (idx >> 2) & 31, c = idx >> 7;
        P[OFF_L0I + idx] = Wih0[(g * 32 + j) * 10 + c];
    }
    for (int idx = tid; idx < 4096; idx += stride) {
        int g = idx & 3, j = (idx >> 2) & 31, k = idx >> 7;
        P[OFF_L0H + idx] = Whh0[(g * 32 + j) * 32 + k];
        P[OFF_L1I + idx] = Wih1[(g * 32 + j) * 32 + k];
        P[OFF_L1H + idx] = Whh1[(g * 32 + j) * 32 + k];
    }
    for (int idx = tid; idx < 128; idx += stride) {
        int g = idx & 3, j = idx >> 2;
        P[OFF_B0 + idx] = bih0[g * 32 + j] + bhh0[g * 32 + j];
        P[OFF_B1 + idx] = bih1[g * 32 + j] + bhh1[g * 32 + j];
    }
    // fc1 k-major [k][ch]
    for (int idx = tid; idx < 2048; idx += stride) {
        int ch = idx & 63, k = idx >> 6;
        P[OFF_FC1W + idx] = fc1w[ch * 32 + k];
    }
    for (int i = tid; i < 64; i += stride) P[OFF_FC1B + i] = fc1b[i];
    // conv: straight copy, [k][ci][co] (convw native layout)
    for (int idx = tid; idx < 16384; idx += stride)
        P[OFF_CWT2 + idx] = convw[idx];
    for (int i = tid; i < 256; i += stride) P[OFF_CB + i] = convb[i];
    for (int idx = tid; idx < 2048; idx += stride) {
        int e = idx >> 1, h = idx & 1, m2 = e >> 6, ch = e & 63;
        P[OFF_FC2W2 + idx] = fc2w[(2 * m2 + h) * 64 + ch];
    }
    for (int i = tid; i < 32;  i += stride) P[OFF_FC2B + i] = fc2b[i];
    for (int idx = tid; idx < 320; idx += stride) {
        int q = idx & 3, e = idx >> 2, oc2 = e >> 4, m2 = e & 15;
        int oc = 2 * oc2 + (q & 1), m = 2 * m2 + (q >> 1);
        P[OFF_FC3W4 + idx] = fc3w[oc * 32 + m];
    }
    for (int i = tid; i < 10; i += stride) P[OFF_FC3B + i] = fc3b[i];
    for (int idx = tid; idx < 8; idx += stride) {
        int k = idx >> 1;
        float g = gparam[k];
        float denom = g * g + 1e-8f;
        float a = (idx & 1) ? eattr[0] : eattr[STRAIGHT_ATTR_IDX];
        P[OFF_GW + idx] = __expf(-(a * a) / denom);
    }
}

// ---------------- LSTM: 4-way wave j-split (R7 exact — ~330us floor) ----------------
// Settled R0-R13: the SGPR-weight v_fma stream costs ~4 issue-cyc/FMA; the
// cost is invariant under px-pairing (R13), not an AGPR-companion tax (R9),
// not launch_bounds-addressable (R8). Structural floor at HIP source level.
#define ROW_ACC32(WBASE, SVAL) do {                                 \
    const float* wr_ = (WBASE); float sv_ = (SVAL);                 \
    _Pragma("unroll")                                               \
    for (int q_ = 0; q_ < 32; q_++)                                 \
        z[q_] = __builtin_fmaf(wr_[q_], sv_, z[q_]);                \
    } while (0)

__global__ __launch_bounds__(256, 1)
void lstm_fc1_kernel(const float* __restrict__ x,
                     const float* __restrict__ P,
                     float* __restrict__ feats) {
    __shared__ float H0[HH * 64];    // 8192 B  [j][lane]
    __shared__ float H1[HH * 64];    // 8192 B  (total 16384)

    int tid  = threadIdx.x;
    int w    = __builtin_amdgcn_readfirstlane(tid >> 6);  // wave id 0..3
    int lane = tid & 63;             // pixel column within block
    int jw   = w << 3;               // first owned unit (0,8,16,24)
    int w32  = w << 5;               // float offset into 128-wide gate rows

    int n = blockIdx.x * 64 + lane;
    int b = n >> 16;
    int pix = n & (NPIX - 1);
    const float* xb = x + (size_t)b * TT * CC * NPIX + pix;

    float c0[8], c1[8];
#pragma unroll
    for (int j = 0; j < 8; j++) {
        c0[j] = 0.f; c1[j] = 0.f;
        H0[(jw + j) * 64 + lane] = 0.f;
        H1[(jw + j) * 64 + lane] = 0.f;
    }
    __syncthreads();

#pragma unroll 1
    for (int t = 0; t < TT; t++) {
        float xcur[CC];
#pragma unroll
        for (int c = 0; c < CC; c++)
            xcur[c] = xb[(size_t)(t * CC + c) * NPIX];

        // ---- layer 0 ----
        {
            float z[32];             // [j_local*4+g], g=(i,f,g,o)
            const float* bb = P + OFF_B0 + w32;
#pragma unroll
            for (int q = 0; q < 32; q++) z[q] = bb[q];
#pragma unroll 1
            for (int c = 0; c < CC; c++)
                ROW_ACC32(P + OFF_L0I + c * 128 + w32, xcur[c]);
#pragma unroll 1
            for (int k = 0; k < HH; k++) {
                float hv = H0[k * 64 + lane];     // h0(t-1)
                ROW_ACC32(P + OFF_L0H + k * 128 + w32, hv);
            }
            __syncthreads();                      // all waves done reading old H0
#pragma unroll
            for (int j = 0; j < 8; j++) {
                float cn = sigf(z[4 * j + 1]) * c0[j]
                         + sigf(z[4 * j + 0]) * tanhf_(z[4 * j + 2]);
                c0[j] = cn;
                H0[(jw + j) * 64 + lane] = sigf(z[4 * j + 3]) * tanhf_(cn);
            }
            __syncthreads();                      // new H0 visible
        }

        // ---- layer 1 ----
        {
            float z[32];
            const float* bb = P + OFF_B1 + w32;
#pragma unroll
            for (int q = 0; q < 32; q++) z[q] = bb[q];
#pragma unroll 1
            for (int k = 0; k < HH; k++) {
                float hv = H0[k * 64 + lane];     // h0(t)
                ROW_ACC32(P + OFF_L1I + k * 128 + w32, hv);
            }
#pragma unroll 1
            for (int k = 0; k < HH; k++) {
                float hv = H1[k * 64 + lane];     // h1(t-1)
                ROW_ACC32(P + OFF_L1H + k * 128 + w32, hv);
            }
            __syncthreads();                      // all waves done reading old H1
#pragma unroll
            for (int j = 0; j < 8; j++) {
                float cn = sigf(z[4 * j + 1]) * c1[j]
                         + sigf(z[4 * j + 0]) * tanhf_(z[4 * j + 2]);
                c1[j] = cn;
                H1[(jw + j) * 64 + lane] = sigf(z[4 * j + 3]) * tanhf_(cn);
            }
            __syncthreads();                      // new H1 visible
        }
    }

    // ---- fc1 + relu: wave w computes ch in [16w, 16w+16) ----
    float f[16];
    {
        const float* fb1 = P + OFF_FC1B + (w << 4);
#pragma unroll
        for (int m = 0; m < 16; m++) f[m] = fb1[m];
    }
#pragma unroll 1
    for (int k = 0; k < HH; k++) {
        float hv = H1[k * 64 + lane];
        const float* wr = P + OFF_FC1W + k * 64 + (w << 4);
#pragma unroll
        for (int m = 0; m < 16; m++)
            f[m] = __builtin_fmaf(wr[m], hv, f[m]);
    }
    float* fob = feats + (size_t)b * WIDTH * NPIX + (size_t)(w * 16) * NPIX + pix;
#pragma unroll
    for (int m = 0; m < 16; m++)
        fob[(size_t)m * NPIX] = fmaxf(f[m], 0.f);
}

// ---------------- fused conv layer (R15 exact: U-in-LDS, 4 px x 16 outs, unroll 2) ----------------
__global__ __launch_bounds__(256, 1)
void conv_fused_kernel(const float* __restrict__ Fin, float* __restrict__ Fout,
                       const float* __restrict__ P, int k) {
    __shared__ float US[64 * 256];   // 65536 B  [ci][px]
    __shared__ float CW[64 * 64];    // 16384 B  [ci][co]

    int tid = threadIdx.x;
    {
        const float4* src = (const float4*)(P + OFF_CWT2 + k * 4096);
        float4* dst = (float4*)CW;
        for (int idx = tid; idx < 1024; idx += 256) dst[idx] = src[idx];
    }

    int n = blockIdx.x * 256 + tid;
    int b = n >> 16;
    int pix = n & (NPIX - 1);
    int i = pix >> 8, j = pix & 255;
    float wstr = P[OFF_GW + 2 * k], wdiag = P[OFF_GW + 2 * k + 1];
    float fu = (i > 0) ? wstr : 0.f, fd = (i < 255) ? wstr : 0.f;
    float fl = (j > 0) ? wstr : 0.f, fr = (j < 255) ? wstr : 0.f;
    float ful = (i > 0 && j > 0) ? wdiag : 0.f, fur = (i > 0 && j < 255) ? wdiag : 0.f;
    float fdl = (i < 255 && j > 0) ? wdiag : 0.f, fdr = (i < 255 && j < 255) ? wdiag : 0.f;

    const float* fb = Fin + (size_t)b * WIDTH * NPIX + pix;
#pragma unroll
    for (int ch = 0; ch < WIDTH; ch++) {
        const float* yc = fb + (size_t)ch * NPIX;
        float v = yc[0];
        v += fu * yc[-256] + fd * yc[256] + fl * yc[-1] + fr * yc[1];
        v += ful * yc[-257] + fur * yc[-255] + fdl * yc[255] + fdr * yc[257];
        US[ch * 256 + tid] = v;
    }
    __syncthreads();

    int l = tid & 63;
    int ob16 = (tid >> 6) << 4;          // wave's first output channel
    float4 acc[16];
#pragma unroll
    for (int o = 0; o < 16; o++) {
        float bv = P[OFF_CB + k * 64 + ob16 + o];
        acc[o] = make_float4(bv, bv, bv, bv);
    }
    const float4* US4 = (const float4*)US;
#pragma unroll 2
    for (int ci = 0; ci < 64; ci++) {
        float4 u4 = US4[ci * 64 + l];
        const float4* wr4 = (const float4*)(CW + ci * 64 + ob16);
#pragma unroll
        for (int q = 0; q < 4; q++) {
            float4 wq = wr4[q];
            acc[4 * q + 0].x = __builtin_fmaf(wq.x, u4.x, acc[4 * q + 0].x);
            acc[4 * q + 0].y = __builtin_fmaf(wq.x, u4.y, acc[4 * q + 0].y);
            acc[4 * q + 0].z = __builtin_fmaf(wq.x, u4.z, acc[4 * q + 0].z);
            acc[4 * q + 0].w = __builtin_fmaf(wq.x, u4.w, acc[4 * q + 0].w);
            acc[4 * q + 1].x = __builtin_fmaf(wq.y, u4.x, acc[4 * q + 1].x);
            acc[4 * q + 1].y = __builtin_fmaf(wq.y, u4.y, acc[4 * q + 1].y);
            acc[4 * q + 1].z = __builtin_fmaf(wq.y, u4.z, acc[4 * q + 1].z);
            acc[4 * q + 1].w = __builtin_fmaf(wq.y, u4.w, acc[4 * q + 1].w);
            acc[4 * q + 2].x = __builtin_fmaf(wq.z, u4.x, acc[4 * q + 2].x);
            acc[4 * q + 2].y = __builtin_fmaf(wq.z, u4.y, acc[4 * q + 2].y);
            acc[4 * q + 2].z = __builtin_fmaf(wq.z, u4.z, acc[4 * q + 2].z);
            acc[4 * q + 2].w = __builtin_fmaf(wq.z, u4.w, acc[4 * q + 2].w);
            acc[4 * q + 3].x = __builtin_fmaf(wq.w, u4.x, acc[4 * q + 3].x);
            acc[4 * q + 3].y = __builtin_fmaf(wq.w, u4.y, acc[4 * q + 3].y);
            acc[4 * q + 3].z = __builtin_fmaf(wq.w, u4.z, acc[4 * q + 3].z);
            acc[4 * q + 3].w = __builtin_fmaf(wq.w, u4.w, acc[4 * q + 3].w);
        }
    }

    int pn = blockIdx.x * 256 + 4 * l;   // first of this lane's 4 pixels
    int pb = pn >> 16;
    int ppix = pn & (NPIX - 1);
    float* ob = Fout + (size_t)pb * WIDTH * NPIX + ppix;
#pragma unroll
    for (int o = 0; o < 16; o++) {
        float4 r;
        r.x = fmaxf(acc[o].x, 0.f); r.y = fmaxf(acc[o].y, 0.f);
        r.z = fmaxf(acc[o].z, 0.f); r.w = fmaxf(acc[o].w, 0.f);
        *(float4*)(ob + (size_t)(ob16 + o) * NPIX) = r;
    }
}

// ---------------- last conv (no relu) + fc2/fc3: R12-style GEMM + LDS reuse ----------------
// The head's conv part was still the pre-R12 per-pixel broadcast GEMM (1024
// ds_read_b128/lane). Restructure: stencil -> US; R12 4px/lane GEMM (no relu,
// CW straight [ci][co]); barrier; write f back into the US region ([ch][px])
// and stage fc2/fc3 params into the dead CW region; barrier; per-pixel fc2/fc3
// exactly as before (f reads stride-1, conflict-free). Conv contraction stays
// ci-ascending per output -> bit-identical f; fc2/fc3 unchanged.
__global__ __launch_bounds__(256, 1)
void conv_head_kernel(const float* __restrict__ Fin, const float* __restrict__ P,
                      float* __restrict__ out) {
    const int k = 3;
    __shared__ float US[64 * 256];   // 65536 B: u-values, then reused for f-values
    __shared__ float CW[64 * 64];    // 16384 B: conv W [ci][co], then fc2/fc3 params

    int tid = threadIdx.x;
    {
        const float4* src = (const float4*)(P + OFF_CWT2 + k * 4096);
        float4* dst = (float4*)CW;
        for (int idx = tid; idx < 1024; idx += 256) dst[idx] = src[idx];
    }

    int n = blockIdx.x * 256 + tid;
    int b = n >> 16;
    int pix = n & (NPIX - 1);
    int i = pix >> 8, j = pix & 255;
    float wstr = P[OFF_GW + 2 * k], wdiag = P[OFF_GW + 2 * k + 1];
    float fu = (i > 0) ? wstr : 0.f, fd = (i < 255) ? wstr : 0.f;
    float fl = (j > 0) ? wstr : 0.f, fr = (j < 255) ? wstr : 0.f;
    float ful = (i > 0 && j > 0) ? wdiag : 0.f, fur = (i > 0 && j < 255) ? wdiag : 0.f;
    float fdl = (i < 255 && j > 0) ? wdiag : 0.f, fdr = (i < 255 && j < 255) ? wdiag : 0.f;

    const float* fbp = Fin + (size_t)b * WIDTH * NPIX + pix;
#pragma unroll
    for (int ch = 0; ch < WIDTH; ch++) {
        const float* yc = fbp + (size_t)ch * NPIX;
        float v = yc[0];
        v += fu * yc[-256] + fd * yc[256] + fl * yc[-1] + fr * yc[1];
        v += ful * yc[-257] + fur * yc[-255] + fdl * yc[255] + fdr * yc[257];
        US[ch * 256 + tid] = v;
    }
    __syncthreads();

    // ---- conv GEMM (R12 pattern, NO relu): lane l owns px 4l..4l+3 ----
    int l = tid & 63;
    int ob16 = (tid >> 6) << 4;
    float4 acc[16];
#pragma unroll
    for (int o = 0; o < 16; o++) {
        float bv = P[OFF_CB + k * 64 + ob16 + o];
        acc[o] = make_float4(bv, bv, bv, bv);
    }
    const float4* US4 = (const float4*)US;
#pragma unroll 2
    for (int ci = 0; ci < 64; ci++) {
        float4 u4 = US4[ci * 64 + l];
        const float4* wr4 = (const float4*)(CW + ci * 64 + ob16);
#pragma unroll
        for (int q = 0; q < 4; q++) {
            float4 wq = wr4[q];
            acc[4 * q + 0].x = __builtin_fmaf(wq.x, u4.x, acc[4 * q + 0].x);
            acc[4 * q + 0].y = __builtin_fmaf(wq.x, u4.y, acc[4 * q + 0].y);
            acc[4 * q + 0].z = __builtin_fmaf(wq.x, u4.z, acc[4 * q + 0].z);
            acc[4 * q + 0].w = __builtin_fmaf(wq.x, u4.w, acc[4 * q + 0].w);
            acc[4 * q + 1].x = __builtin_fmaf(wq.y, u4.x, acc[4 * q + 1].x);
            acc[4 * q + 1].y = __builtin_fmaf(wq.y, u4.y, acc[4 * q + 1].y);
            acc[4 * q + 1].z = __builtin_fmaf(wq.y, u4.z, acc[4 * q + 1].z);
            acc[4 * q + 1].w = __builtin_fmaf(wq.y, u4.w, acc[4 * q + 1].w);
            acc[4 * q + 2].x = __builtin_fmaf(wq.z, u4.x, acc[4 * q + 2].x);
            acc[4 * q + 2].y = __builtin_fmaf(wq.z, u4.y, acc[4 * q + 2].y);
            acc[4 * q + 2].z = __builtin_fmaf(wq.z, u4.z, acc[4 * q + 2].z);
            acc[4 * q + 2].w = __builtin_fmaf(wq.z, u4.w, acc[4 * q + 2].w);
            acc[4 * q + 3].x = __builtin_fmaf(wq.w, u4.x, acc[4 * q + 3].x);
            acc[4 * q + 3].y = __builtin_fmaf(wq.w, u4.y, acc[4 * q + 3].y);
            acc[4 * q + 3].z = __builtin_fmaf(wq.w, u4.z, acc[4 * q + 3].z);
            acc[4 * q + 3].w = __builtin_fmaf(wq.w, u4.w, acc[4 * q + 3].w);
        }
    }
    __syncthreads();    // all US/CW reads complete -> safe to repurpose both

    // ---- write f into US ([ch][px]); stage fc2/fc3 params into CW region ----
#pragma unroll
    for (int o = 0; o < 16; o++)
        *(float4*)&US[(ob16 + o) * 256 + 4 * l] = acc[o];
    {
        float4* f2w = (float4*)CW;                       // 512 float4 (8 KB)
        const float4* s2 = (const float4*)(P + OFF_FC2W2);
        for (int idx = tid; idx < 512; idx += 256) f2w[idx] = s2[idx];
        float4* f3w = (float4*)(CW + 2048);              // 80 float4
        const float4* s3 = (const float4*)(P + OFF_FC3W4);
        if (tid < 80) f3w[tid] = s3[tid];
        if (tid < 32) CW[2048 + 320 + tid] = P[OFF_FC2B + tid];
        if (tid < 10) CW[2048 + 352 + tid] = P[OFF_FC3B + tid];
    }
    __syncthreads();

    // ---- per-pixel fc2 + relu + fc3 (thread = pixel tid) ----
    float f[WIDTH];
#pragma unroll
    for (int ch = 0; ch < WIDTH; ch++) f[ch] = US[ch * 256 + tid];

    const float4* F2W = (const float4*)CW;
    const float4* F3W = (const float4*)(CW + 2048);
    const float*  F2B = CW + 2048 + 320;
    const float*  F3B = CW + 2048 + 352;

    float2 oo[5];
#pragma unroll
    for (int oc2 = 0; oc2 < 5; oc2++) oo[oc2] = make_float2(F3B[2 * oc2], F3B[2 * oc2 + 1]);
#pragma unroll 1
    for (int m2 = 0; m2 < 16; m2++) {
        float ax = F2B[2 * m2], ay = F2B[2 * m2 + 1];
        const float4* wv = F2W + m2 * 32;
#pragma unroll
        for (int ch2 = 0; ch2 < 32; ch2++) {
            float4 q = wv[ch2];
            ax = __builtin_fmaf(q.x, f[2 * ch2], ax); ax = __builtin_fmaf(q.z, f[2 * ch2 + 1], ax);
            ay = __builtin_fmaf(q.y, f[2 * ch2], ay); ay = __builtin_fmaf(q.w, f[2 * ch2 + 1], ay);
        }
        ax = fmaxf(ax, 0.f); ay = fmaxf(ay, 0.f);
#pragma unroll
        for (int oc2 = 0; oc2 < 5; oc2++) {
            float4 q = F3W[oc2 * 16 + m2];
            oo[oc2].x += q.x * ax + q.z * ay;
            oo[oc2].y += q.y * ax + q.w * ay;
        }
    }
    float* ob = out + (size_t)b * OUTC * NPIX + pix;
#pragma unroll
    for (int oc2 = 0; oc2 < 5; oc2++) {
        ob[(size_t)(2 * oc2) * NPIX]     = oo[oc2].x;
        ob[(size_t)(2 * oc2 + 1) * NPIX] = oo[oc2].y;
    }
}

extern "C" void kernel_launch(void* const* d_in, const int* in_sizes, int n_in,
                              void* d_out, int out_size, void* d_ws, size_t ws_size,
                              hipStream_t stream) {
    const float* x     = (const float*)d_in[0];
    const float* eattr = (const float*)d_in[3];
    const float* Wih0  = (const float*)d_in[4];
    const float* Whh0  = (const float*)d_in[5];
    const float* bih0  = (const float*)d_in[6];
    const float* bhh0  = (const float*)d_in[7];
    const float* Wih1  = (const float*)d_in[8];
    const float* Whh1  = (const float*)d_in[9];
    const float* bih1  = (const float*)d_in[10];
    const float* bhh1  = (const float*)d_in[11];
    const float* fc1w  = (const float*)d_in[12];
    const float* fc1b  = (const float*)d_in[13];
    const float* convw = (const float*)d_in[14];
    const float* convb = (const float*)d_in[15];
    const float* gparam= (const float*)d_in[16];
    const float* fc2w  = (const float*)d_in[17];
    const float* fc2b  = (const float*)d_in[18];
    const float* fc3w  = (const float*)d_in[19];
    const float* fc3b  = (const float*)d_in[20];

    float* P  = (float*)d_ws;
    float* FA = P + OFF_FEATS_A;
    float* FB = P + OFF_FEATS_B;

    prep_kernel<<<64, 256, 0, stream>>>(Wih0, Whh0, bih0, bhh0, Wih1, Whh1, bih1, bhh1,
                                        fc1w, fc1b, convw, convb, fc2w, fc2b, fc3w, fc3b,
                                        gparam, eattr, P);
    lstm_fc1_kernel<<<2048, 256, 0, stream>>>(x, P, FA);
    conv_fused_kernel<<<512, 256, 0, stream>>>(FA, FB, P, 0);
    conv_fused_kernel<<<512, 256, 0, stream>>>(FB, FA, P, 1);
    conv_fused_kernel<<<512, 256, 0, stream>>>(FA, FB, P, 2);
    conv_head_kernel<<<512, 256, 0, stream>>>(FB, P, (float*)d_out);
}